// Round 1
// 329.860 us; speedup vs baseline: 1.0934x; 1.0934x over previous
//
#include <hip/hip_runtime.h>

// FlashFFTConvND == depthwise linear 2D conv (circular 256-pad == linear since
// 128+64-1 <= 256):  y[i][j] = postgate * sum_{p,q} x[i-p][j-q] * k[p][q].
//
// R4: interleaved-tile decomposition + zero-block skipping.
//  - wave (iw,jw) owns i-blocks {32nt+16iw}, j-blocks {32mt+16jw} (stride-32
//    interleave). Per (r,nt) the kernel-row window [32nt+16iw-r, +15-r] is
//    tested against [0,64) with a wave-uniform branch: skips the ~45% of R3's
//    MFMAs that multiplied guaranteed-zero pad rows. Per-wave MFMA counts
//    1554/1554/1778/1778 (R3: 2048/2048/4064/4064) -> balance + fewer issues.
//  - stride-32 j-blocks make A-windows (d = 32mt+16jw-32q1) dedup to 4 shared
//    windows/wave (R3: 6); all reads from ONE vaddr + imm offsets.
//  - out-of-range kernel rows all map to a single zero row -> kpad 65 rows;
//    xls halo trimmed to 32 cols. LDS 62688 -> 50320 B => 3 blocks/CU.

typedef unsigned int uint32;
typedef short short8 __attribute__((ext_vector_type(8)));
typedef float float4v __attribute__((ext_vector_type(4)));
typedef uint32 uint4v __attribute__((ext_vector_type(4)));

__device__ __forceinline__ unsigned short f2bf(float f) {
    uint32 x = __float_as_uint(f);
    uint32 r = (x + 0x7fffu + ((x >> 16) & 1u)) >> 16;
    return (unsigned short)r;
}

#define XLS_PITCH 160
#define XLS_BYTES (128 * XLS_PITCH * 2)      // 40960
#define KPAD_BYTES (65 * 72 * 2)             // 9360
#define SMEM_BYTES (XLS_BYTES + KPAD_BYTES)  // 50320 -> 3 blocks/CU (rounds to 50688)

__global__ __launch_bounds__(256, 3)
void conv_mfma4(const float* __restrict__ u, const float* __restrict__ kk,
                const float* __restrict__ pregate, const float* __restrict__ postgate,
                float* __restrict__ out)
{
    extern __shared__ char smem[];
    // xls[r][c] = x[r][127 - c]; cols [128,160) = zero halo. Pitch 320B.
    unsigned short (*xls)[XLS_PITCH] = (unsigned short(*)[XLS_PITCH])smem;
    // kpad[0][*] = zero sink for all out-of-range kernel rows; rows 1..64 = k.
    unsigned short (*kpad)[72] = (unsigned short(*)[72])(smem + XLS_BYTES);

    const int img = blockIdx.x;            // b*256 + c
    const int c   = img & 255;
    const int tid = threadIdx.x;

    const float* uimg = u        + (size_t)img * (128*128);
    const float* pimg = pregate  + (size_t)img * (128*128);
    const float* gimg = postgate + (size_t)img * (128*128);
    float*       oimg = out      + (size_t)img * (128*128);
    const float* kimg = kk       + (size_t)c   * (64*64);

    const uint4 z = make_uint4(0u,0u,0u,0u);
    // ---- stage: kpad zero row 0 (the clamp sink) ----
    if (tid < 9) ((uint4*)&kpad[0][0])[tid] = z;
    // ---- stage: xls zero halo, cols [128,160) ----
    for (int t = tid; t < 512; t += 256) {
        int r = t >> 2, cc = 128 + ((t & 3) << 3);
        *(uint4*)&xls[r][cc] = z;
    }
    // ---- stage: xls values (reversed): xls[r][120-c8+d] = x[r][c8+7-d] ----
    for (int t = tid; t < 128*16; t += 256) {
        int r = t >> 4, c8 = (t & 15) << 3;
        const float4 u0 = *(const float4*)(uimg + r*128 + c8);
        const float4 u1 = *(const float4*)(uimg + r*128 + c8 + 4);
        const float4 p0 = *(const float4*)(pimg + r*128 + c8);
        const float4 p1 = *(const float4*)(pimg + r*128 + c8 + 4);
        unsigned short h0 = f2bf(u0.x*p0.x), h1 = f2bf(u0.y*p0.y);
        unsigned short h2 = f2bf(u0.z*p0.z), h3 = f2bf(u0.w*p0.w);
        unsigned short h4 = f2bf(u1.x*p1.x), h5 = f2bf(u1.y*p1.y);
        unsigned short h6 = f2bf(u1.z*p1.z), h7 = f2bf(u1.w*p1.w);
        uint4 w;
        w.x = (uint32)h7 | ((uint32)h6 << 16);
        w.y = (uint32)h5 | ((uint32)h4 << 16);
        w.z = (uint32)h3 | ((uint32)h2 << 16);
        w.w = (uint32)h1 | ((uint32)h0 << 16);
        *(uint4*)&xls[r][120 - c8] = w;
    }
    // ---- stage: kpad rows [1,65) = k rows [0,64) ----
    for (int t = tid; t < 64*16; t += 256) {
        int p = t >> 4, c4 = (t & 15) << 2;
        const float4 kv = *(const float4*)(kimg + p*64 + c4);
        uint2 w;
        w.x = (uint32)f2bf(kv.x) | ((uint32)f2bf(kv.y) << 16);
        w.y = (uint32)f2bf(kv.z) | ((uint32)f2bf(kv.w) << 16);
        *(uint2*)&kpad[1 + p][c4] = w;
    }
    __syncthreads();

    // ---- K-loop ----
    const int wv   = tid >> 6;
    const int lane = tid & 63;
    const int jw = wv >> 1;                                 // j-block parity
    const int iw = (wv & 1) ^ ((blockIdx.x >> 8) & 1);      // i-block parity, SIMD balance
    const int m    = lane & 15;
    const int quad = lane >> 4;
    const int i16  = iw << 4;

    // A windows: widx holds xls cols [c0-32*widx, +7]; shared by (mt,q1=0)->widx=mt
    // and (mt,q1=1)->widx=mt-1. (mt=0,q1=1) is all-halo => statically skipped.
    const int c0    = 127 - (jw << 4) - m + (quad << 3);
    const uint32 sh = (uint32)((c0 & 1) << 4);              // alignbit shift 0/16
    const int bw3   = (c0 >> 1) - 48;                       // widx=3 base dword
    const int rhi   = 111 + i16;                            // 111 (iw=0) / 127 (iw=1)

    const uint32* xls32 = (const uint32*)smem;              // 80 dwords/row

    float4v acc[4][4] = {};                                 // [mt][nt], static idx

#pragma unroll 1
    for (int r = 0; r <= rhi; ++r) {
        const uint32* row32 = xls32 + r*80 + bw3;
        uint32 dw[4][5];
#pragma unroll
        for (int w = 0; w < 4; ++w) {
            const int O = (3 - w) << 4;                     // imm offsets 0..52 dwords
            dw[w][0] = row32[O+0]; dw[w][1] = row32[O+1];
            dw[w][2] = row32[O+2]; dw[w][3] = row32[O+3];
            dw[w][4] = row32[O+4];
        }
        short8 av[4];
#pragma unroll
        for (int w = 0; w < 4; ++w) {
            uint4v f;
            f.x = __builtin_amdgcn_alignbit(dw[w][1], dw[w][0], sh);
            f.y = __builtin_amdgcn_alignbit(dw[w][2], dw[w][1], sh);
            f.z = __builtin_amdgcn_alignbit(dw[w][3], dw[w][2], sh);
            f.w = __builtin_amdgcn_alignbit(dw[w][4], dw[w][3], sh);
            av[w] = __builtin_bit_cast(short8, f);
        }

        const int t0 = i16 + m - r;
#pragma unroll
        for (int nt = 0; nt < 4; ++nt) {
            const int nb = (nt << 5) + i16;
            if (r < nb - 63 || r > nb + 15) continue;       // wave-uniform skip
            const int p   = t0 + (nt << 5);                 // kernel row, per-lane
            const int row = ((uint32)p < 64u) ? (p + 1) : 0;
            const short8 bv0 = *(const short8*)&kpad[row][quad << 3];
            const short8 bv1 = *(const short8*)&kpad[row][32 + (quad << 3)];
            acc[0][nt] = __builtin_amdgcn_mfma_f32_16x16x32_bf16(av[0], bv0, acc[0][nt], 0,0,0);
            acc[1][nt] = __builtin_amdgcn_mfma_f32_16x16x32_bf16(av[1], bv0, acc[1][nt], 0,0,0);
            acc[2][nt] = __builtin_amdgcn_mfma_f32_16x16x32_bf16(av[2], bv0, acc[2][nt], 0,0,0);
            acc[3][nt] = __builtin_amdgcn_mfma_f32_16x16x32_bf16(av[3], bv0, acc[3][nt], 0,0,0);
            acc[1][nt] = __builtin_amdgcn_mfma_f32_16x16x32_bf16(av[0], bv1, acc[1][nt], 0,0,0);
            acc[2][nt] = __builtin_amdgcn_mfma_f32_16x16x32_bf16(av[1], bv1, acc[2][nt], 0,0,0);
            acc[3][nt] = __builtin_amdgcn_mfma_f32_16x16x32_bf16(av[2], bv1, acc[3][nt], 0,0,0);
        }
    }

    // ---- epilogue: acc -> LDS transpose -> postgate * store ----
    // i = 32nt + 16iw + m ; j = 32mt + 16jw + 4quad + rg.
    __syncthreads();
    float (*bufE)[132] = (float(*)[132])smem;   // 64x132 fp32 = 33792 B
#pragma unroll
    for (int h = 0; h < 2; ++h) {               // i halves [0,64), [64,128)
#pragma unroll
        for (int ntl = 0; ntl < 2; ++ntl) {
            const int iloc = (ntl << 5) + i16 + m;
#pragma unroll
            for (int mt = 0; mt < 4; ++mt)
#pragma unroll
                for (int rg = 0; rg < 4; ++rg)
                    bufE[iloc][(mt << 5) + (jw << 4) + (quad << 2) + rg] =
                        acc[mt][(h << 1) + ntl][rg];
        }
        __syncthreads();
#pragma unroll 1
        for (int s = 0; s < 8; ++s) {
            int chunk = (s << 8) + tid;
            int row = chunk >> 5, c4 = (chunk & 31) << 2;
            float4 v = *(float4*)&bufE[row][c4];
            int gi = (h << 6) + row;
            const float4 g = *(const float4*)(gimg + gi*128 + c4);
            float4 o;
            o.x = v.x*g.x; o.y = v.y*g.y; o.z = v.z*g.z; o.w = v.w*g.w;
            *(float4*)(oimg + gi*128 + c4) = o;
        }
        __syncthreads();
    }
}

extern "C" void kernel_launch(void* const* d_in, const int* in_sizes, int n_in,
                              void* d_out, int out_size, void* d_ws, size_t ws_size,
                              hipStream_t stream) {
    const float* u    = (const float*)d_in[0];  // (4,256,128,128)
    const float* k    = (const float*)d_in[1];  // (256,64,64)
    const float* pre  = (const float*)d_in[2];  // (4,256,128,128)
    const float* post = (const float*)d_in[3];  // (4,256,128,128)
    float* out = (float*)d_out;                 // (4,256,128,128) fp32

    conv_mfma4<<<dim3(1024), dim3(256), SMEM_BYTES, stream>>>(u, k, pre, post, out);
}

// Round 2
// 316.417 us; speedup vs baseline: 1.1398x; 1.0425x over previous
//
#include <hip/hip_runtime.h>

// FlashFFTConvND == depthwise linear 2D conv (circular 256-pad == linear since
// 128+64-1 <= 256):  y[i][j] = postgate * sum_{p,q} x[i-p][j-q] * k[p][q].
//
// R5: occupancy fix. R4 measured OccupancyPercent=25.5%: 50.3KB LDS -> 3
// blocks/CU resident vs grid=4 blocks/CU of work => half the kernel ran 1
// block/CU (makespan 2t). Shrink LDS to exactly 40960B -> 4 blocks/CU, grid
// 1024 = exact fit, 16 waves/CU, no tail.
//  - xls halo dropped (pitch 160->128): out-of-range cols of the rightmost
//    A-window (av[0]) are zeroed by a precomputed per-lane mask (4 v_and/iter)
//    instead of stored zeros. Overflow reads land in the next LDS row: garbage
//    but masked, math identical.
//  - kpad zero row dropped, pitch 72->64 with 16B-granule XOR swizzle
//    (g^=p&7): conflict-free reads (R4's pitch-144 was ~8-way, 8.8M conflict
//    cycles). Out-of-range kernel rows: address wraps (p&63), B-frag zeroed by
//    cndmask only on the ~38% of (r,nt) with a partial window (uniform branch).

typedef unsigned int uint32;
typedef short short8 __attribute__((ext_vector_type(8)));
typedef float float4v __attribute__((ext_vector_type(4)));
typedef uint32 uint4v __attribute__((ext_vector_type(4)));

__device__ __forceinline__ unsigned short f2bf(float f) {
    uint32 x = __float_as_uint(f);
    uint32 r = (x + 0x7fffu + ((x >> 16) & 1u)) >> 16;
    return (unsigned short)r;
}

#define XLS_BYTES (128 * 128 * 2)            // 32768, pitch 128 shorts (no halo)
#define KPAD_BYTES (64 * 64 * 2)             // 8192, pitch 64 shorts, swizzled
#define SMEM_BYTES (XLS_BYTES + KPAD_BYTES)  // 40960 -> 4 blocks/CU exactly

__global__ __launch_bounds__(256, 4)
void conv_mfma5(const float* __restrict__ u, const float* __restrict__ kk,
                const float* __restrict__ pregate, const float* __restrict__ postgate,
                float* __restrict__ out)
{
    extern __shared__ char smem[];
    // xls[r][c] = x[r][127 - c]; no halo.
    unsigned short (*xls)[128] = (unsigned short(*)[128])smem;
    // kpad[p][*]: kernel row p, 16B granule g stored at g ^ (p & 7).
    unsigned short (*kpad)[64] = (unsigned short(*)[64])(smem + XLS_BYTES);

    const int img = blockIdx.x;            // b*256 + c
    const int c   = img & 255;
    const int tid = threadIdx.x;

    const float* uimg = u        + (size_t)img * (128*128);
    const float* pimg = pregate  + (size_t)img * (128*128);
    const float* gimg = postgate + (size_t)img * (128*128);
    float*       oimg = out      + (size_t)img * (128*128);
    const float* kimg = kk       + (size_t)c   * (64*64);

    // ---- stage: xls values (reversed): xls[r][120-c8+d] = x[r][c8+7-d] ----
    for (int t = tid; t < 128*16; t += 256) {
        int r = t >> 4, c8 = (t & 15) << 3;
        const float4 u0 = *(const float4*)(uimg + r*128 + c8);
        const float4 u1 = *(const float4*)(uimg + r*128 + c8 + 4);
        const float4 p0 = *(const float4*)(pimg + r*128 + c8);
        const float4 p1 = *(const float4*)(pimg + r*128 + c8 + 4);
        unsigned short h0 = f2bf(u0.x*p0.x), h1 = f2bf(u0.y*p0.y);
        unsigned short h2 = f2bf(u0.z*p0.z), h3 = f2bf(u0.w*p0.w);
        unsigned short h4 = f2bf(u1.x*p1.x), h5 = f2bf(u1.y*p1.y);
        unsigned short h6 = f2bf(u1.z*p1.z), h7 = f2bf(u1.w*p1.w);
        uint4 w;
        w.x = (uint32)h7 | ((uint32)h6 << 16);
        w.y = (uint32)h5 | ((uint32)h4 << 16);
        w.z = (uint32)h3 | ((uint32)h2 << 16);
        w.w = (uint32)h1 | ((uint32)h0 << 16);
        *(uint4*)&xls[r][120 - c8] = w;
    }
    // ---- stage: kpad rows [0,64), granule-swizzled ----
    for (int t = tid; t < 64*16; t += 256) {
        int p = t >> 4, c4 = (t & 15) << 2;       // c4 in {0,4,...,60}
        const float4 kv = *(const float4*)(kimg + p*64 + c4);
        uint2 w;
        w.x = (uint32)f2bf(kv.x) | ((uint32)f2bf(kv.y) << 16);
        w.y = (uint32)f2bf(kv.z) | ((uint32)f2bf(kv.w) << 16);
        int sc = (((c4 >> 3) ^ (p & 7)) << 3) | (c4 & 7);
        *(uint2*)&kpad[p][sc] = w;
    }
    __syncthreads();

    // ---- K-loop ----
    const int wv   = tid >> 6;
    const int lane = tid & 63;
    const int jw = wv >> 1;                                 // j-block parity
    const int iw = (wv & 1) ^ ((blockIdx.x >> 8) & 1);      // i-block parity, SIMD balance
    const int m    = lane & 15;
    const int quad = lane >> 4;
    const int i16  = iw << 4;

    // A windows: av[w] holds xls cols [c0-32w, +7]; (mt,q1=0)->av[mt],
    // (mt,q1=1)->av[mt-1]; (mt=0,q1=1) all-halo => statically skipped.
    const int c0    = 127 - (jw << 4) - m + (quad << 3);
    const uint32 sh = (uint32)((c0 & 1) << 4);              // alignbit shift 0/16
    const int bw3   = (c0 >> 1) - 48;                       // av[3] base dword
    const int rhi   = 111 + i16;                            // 111 (iw=0) / 127 (iw=1)

    // av[0] = cols c0..c0+7: zero elements with col > 127 (halo replacement).
    const int rem = 127 - c0;                               // elem t valid iff t <= rem
    uint4v amask;
    amask.x = (rem >= 0 ? 0x0000FFFFu : 0u) | (rem >= 1 ? 0xFFFF0000u : 0u);
    amask.y = (rem >= 2 ? 0x0000FFFFu : 0u) | (rem >= 3 ? 0xFFFF0000u : 0u);
    amask.z = (rem >= 4 ? 0x0000FFFFu : 0u) | (rem >= 5 ? 0xFFFF0000u : 0u);
    amask.w = (rem >= 6 ? 0x0000FFFFu : 0u) | (rem >= 7 ? 0xFFFF0000u : 0u);

    const uint32* xls32 = (const uint32*)smem;              // 64 dwords/row
    const short8 kzero = {};

    float4v acc[4][4] = {};                                 // [mt][nt], static idx

#pragma unroll 1
    for (int r = 0; r <= rhi; ++r) {
        const uint32* row32 = xls32 + r*64 + bw3;
        uint32 dw[4][5];
#pragma unroll
        for (int w = 0; w < 4; ++w) {
            const int O = (3 - w) << 4;                     // imm offsets, dwords
            dw[w][0] = row32[O+0]; dw[w][1] = row32[O+1];
            dw[w][2] = row32[O+2]; dw[w][3] = row32[O+3];
            dw[w][4] = row32[O+4];
        }
        short8 av[4];
#pragma unroll
        for (int w = 0; w < 4; ++w) {
            uint4v f;
            f.x = __builtin_amdgcn_alignbit(dw[w][1], dw[w][0], sh);
            f.y = __builtin_amdgcn_alignbit(dw[w][2], dw[w][1], sh);
            f.z = __builtin_amdgcn_alignbit(dw[w][3], dw[w][2], sh);
            f.w = __builtin_amdgcn_alignbit(dw[w][4], dw[w][3], sh);
            if (w == 0) {
                f.x &= amask.x; f.y &= amask.y;
                f.z &= amask.z; f.w &= amask.w;
            }
            av[w] = __builtin_bit_cast(short8, f);
        }

        const int t0 = i16 + m - r;
#pragma unroll
        for (int nt = 0; nt < 4; ++nt) {
            const int nb = (nt << 5) + i16;
            if (r < nb - 63 || r > nb + 15) continue;       // wave-uniform skip
            const int p  = t0 + (nt << 5);                  // kernel row, per-lane
            const int pr = p & 63;                          // wrapped address
            const int px = pr & 7;
            short8 bv0 = *(const short8*)&kpad[pr][(quad ^ px) << 3];
            short8 bv1 = *(const short8*)&kpad[pr][((4 + quad) ^ px) << 3];
            if (r > nb || r < nb - 48) {                    // partial window only
                const bool keep = ((uint32)p < 64u);
                bv0 = keep ? bv0 : kzero;
                bv1 = keep ? bv1 : kzero;
            }
            acc[0][nt] = __builtin_amdgcn_mfma_f32_16x16x32_bf16(av[0], bv0, acc[0][nt], 0,0,0);
            acc[1][nt] = __builtin_amdgcn_mfma_f32_16x16x32_bf16(av[1], bv0, acc[1][nt], 0,0,0);
            acc[2][nt] = __builtin_amdgcn_mfma_f32_16x16x32_bf16(av[2], bv0, acc[2][nt], 0,0,0);
            acc[3][nt] = __builtin_amdgcn_mfma_f32_16x16x32_bf16(av[3], bv0, acc[3][nt], 0,0,0);
            acc[1][nt] = __builtin_amdgcn_mfma_f32_16x16x32_bf16(av[0], bv1, acc[1][nt], 0,0,0);
            acc[2][nt] = __builtin_amdgcn_mfma_f32_16x16x32_bf16(av[1], bv1, acc[2][nt], 0,0,0);
            acc[3][nt] = __builtin_amdgcn_mfma_f32_16x16x32_bf16(av[2], bv1, acc[3][nt], 0,0,0);
        }
    }

    // ---- epilogue: acc -> LDS transpose -> postgate * store ----
    // i = 32nt + 16iw + m ; j = 32mt + 16jw + 4quad + rg.
    __syncthreads();
    float (*bufE)[132] = (float(*)[132])smem;   // 64x132 fp32 = 33792 B
#pragma unroll
    for (int h = 0; h < 2; ++h) {               // i halves [0,64), [64,128)
#pragma unroll
        for (int ntl = 0; ntl < 2; ++ntl) {
            const int iloc = (ntl << 5) + i16 + m;
#pragma unroll
            for (int mt = 0; mt < 4; ++mt)
#pragma unroll
                for (int rg = 0; rg < 4; ++rg)
                    bufE[iloc][(mt << 5) + (jw << 4) + (quad << 2) + rg] =
                        acc[mt][(h << 1) + ntl][rg];
        }
        __syncthreads();
#pragma unroll 1
        for (int s = 0; s < 8; ++s) {
            int chunk = (s << 8) + tid;
            int row = chunk >> 5, c4 = (chunk & 31) << 2;
            float4 v = *(float4*)&bufE[row][c4];
            int gi = (h << 6) + row;
            const float4 g = *(const float4*)(gimg + gi*128 + c4);
            float4 o;
            o.x = v.x*g.x; o.y = v.y*g.y; o.z = v.z*g.z; o.w = v.w*g.w;
            *(float4*)(oimg + gi*128 + c4) = o;
        }
        __syncthreads();
    }
}

extern "C" void kernel_launch(void* const* d_in, const int* in_sizes, int n_in,
                              void* d_out, int out_size, void* d_ws, size_t ws_size,
                              hipStream_t stream) {
    const float* u    = (const float*)d_in[0];  // (4,256,128,128)
    const float* k    = (const float*)d_in[1];  // (256,64,64)
    const float* pre  = (const float*)d_in[2];  // (4,256,128,128)
    const float* post = (const float*)d_in[3];  // (4,256,128,128)
    float* out = (float*)d_out;                 // (4,256,128,128) fp32

    conv_mfma5<<<dim3(1024), dim3(256), SMEM_BYTES, stream>>>(u, k, pre, post, out);
}

// Round 3
// 288.796 us; speedup vs baseline: 1.2489x; 1.0956x over previous
//
#include <hip/hip_runtime.h>

// FlashFFTConvND == depthwise linear 2D conv (circular 256-pad == linear since
// 128+64-1 <= 256):  y[i][j] = postgate * sum_{p,q} x[i-p][j-q] * k[p][q].
//
// R6: branchless static-segment main loop. R5's per-nt `continue` branches
// blocked load hoisting: each valid nt was a serial addr->ds_read->wait->MFMA
// chain (~165cy), and with pipes at 7-20% demand the kernel is latency-bound.
// The nt-validity pattern is piecewise-constant in r: 8 segments per wave
// (S0..S7, boundaries at nb-63/nb-48/nb/nb+15), each nt statically FULL
// (p in [0,63] guaranteed: no &63, no masking) or PARTIAL (wrap + cndmask).
// Straight-line bodies + unroll 2 let all A+B loads of 1-2 iterations issue
// in one burst under the previous iteration's MFMAs.

typedef unsigned int uint32;
typedef short short8 __attribute__((ext_vector_type(8)));
typedef float float4v __attribute__((ext_vector_type(4)));
typedef uint32 uint4v __attribute__((ext_vector_type(4)));

__device__ __forceinline__ unsigned short f2bf(float f) {
    uint32 x = __float_as_uint(f);
    uint32 r = (x + 0x7fffu + ((x >> 16) & 1u)) >> 16;
    return (unsigned short)r;
}

#define XLS_BYTES (128 * 128 * 2)            // 32768, pitch 128 shorts (no halo)
#define KPAD_BYTES (64 * 64 * 2)             // 8192, pitch 64 shorts, swizzled
#define SMEM_BYTES (XLS_BYTES + KPAD_BYTES)  // 40960 -> 4 blocks/CU exactly

__global__ __launch_bounds__(256, 4)
void conv_mfma6(const float* __restrict__ u, const float* __restrict__ kk,
                const float* __restrict__ pregate, const float* __restrict__ postgate,
                float* __restrict__ out)
{
    extern __shared__ char smem[];
    // xls[r][c] = x[r][127 - c]; no halo.
    unsigned short (*xls)[128] = (unsigned short(*)[128])smem;
    // kpad[p][*]: kernel row p, 16B granule g stored at g ^ (p & 7).
    unsigned short (*kpad)[64] = (unsigned short(*)[64])(smem + XLS_BYTES);

    const int img = blockIdx.x;            // b*256 + c
    const int c   = img & 255;
    const int tid = threadIdx.x;

    const float* uimg = u        + (size_t)img * (128*128);
    const float* pimg = pregate  + (size_t)img * (128*128);
    const float* gimg = postgate + (size_t)img * (128*128);
    float*       oimg = out      + (size_t)img * (128*128);
    const float* kimg = kk       + (size_t)c   * (64*64);

    // ---- stage: xls values (reversed): xls[r][120-c8+d] = x[r][c8+7-d] ----
    for (int t = tid; t < 128*16; t += 256) {
        int r = t >> 4, c8 = (t & 15) << 3;
        const float4 u0 = *(const float4*)(uimg + r*128 + c8);
        const float4 u1 = *(const float4*)(uimg + r*128 + c8 + 4);
        const float4 p0 = *(const float4*)(pimg + r*128 + c8);
        const float4 p1 = *(const float4*)(pimg + r*128 + c8 + 4);
        unsigned short h0 = f2bf(u0.x*p0.x), h1 = f2bf(u0.y*p0.y);
        unsigned short h2 = f2bf(u0.z*p0.z), h3 = f2bf(u0.w*p0.w);
        unsigned short h4 = f2bf(u1.x*p1.x), h5 = f2bf(u1.y*p1.y);
        unsigned short h6 = f2bf(u1.z*p1.z), h7 = f2bf(u1.w*p1.w);
        uint4 w;
        w.x = (uint32)h7 | ((uint32)h6 << 16);
        w.y = (uint32)h5 | ((uint32)h4 << 16);
        w.z = (uint32)h3 | ((uint32)h2 << 16);
        w.w = (uint32)h1 | ((uint32)h0 << 16);
        *(uint4*)&xls[r][120 - c8] = w;
    }
    // ---- stage: kpad rows [0,64), granule-swizzled ----
    for (int t = tid; t < 64*16; t += 256) {
        int p = t >> 4, c4 = (t & 15) << 2;       // c4 in {0,4,...,60}
        const float4 kv = *(const float4*)(kimg + p*64 + c4);
        uint2 w;
        w.x = (uint32)f2bf(kv.x) | ((uint32)f2bf(kv.y) << 16);
        w.y = (uint32)f2bf(kv.z) | ((uint32)f2bf(kv.w) << 16);
        int sc = (((c4 >> 3) ^ (p & 7)) << 3) | (c4 & 7);
        *(uint2*)&kpad[p][sc] = w;
    }
    __syncthreads();

    // ---- K-loop ----
    const int wv   = tid >> 6;
    const int lane = tid & 63;
    const int jw = wv >> 1;                                 // j-block parity
    const int iw = (wv & 1) ^ ((blockIdx.x >> 8) & 1);      // i-block parity, SIMD balance
    const int m    = lane & 15;
    const int quad = lane >> 4;
    const int i16  = iw << 4;

    // A windows: av[w] holds xls cols [c0-32w, +7]; (mt,q1=0)->av[mt],
    // (mt,q1=1)->av[mt-1]; (mt=0,q1=1) all-halo => statically skipped.
    const int c0    = 127 - (jw << 4) - m + (quad << 3);
    const uint32 sh = (uint32)((c0 & 1) << 4);              // alignbit shift 0/16
    const int bw3   = (c0 >> 1) - 48;                       // av[3] base dword

    // av[0] = cols c0..c0+7: zero elements with col > 127 (halo replacement).
    const int rem = 127 - c0;                               // elem t valid iff t <= rem
    uint4v amask;
    amask.x = (rem >= 0 ? 0x0000FFFFu : 0u) | (rem >= 1 ? 0xFFFF0000u : 0u);
    amask.y = (rem >= 2 ? 0x0000FFFFu : 0u) | (rem >= 3 ? 0xFFFF0000u : 0u);
    amask.z = (rem >= 4 ? 0x0000FFFFu : 0u) | (rem >= 5 ? 0xFFFF0000u : 0u);
    amask.w = (rem >= 6 ? 0x0000FFFFu : 0u) | (rem >= 7 ? 0xFFFF0000u : 0u);

    const uint32* xls32 = (const uint32*)smem;              // 64 dwords/row
    const char*   kpadB = (const char*)kpad;
    const short8  kzero = {};

    float4v acc[4][4] = {};                                 // [mt][nt], static idx

#define A_PHASE(rr) \
    short8 av[4]; \
    { const uint32* row32 = xls32 + (rr)*64 + bw3; \
      _Pragma("unroll") \
      for (int w = 0; w < 4; ++w) { \
        const int O = (3 - w) << 4; \
        uint32 d0=row32[O+0], d1=row32[O+1], d2=row32[O+2], d3=row32[O+3], d4=row32[O+4]; \
        uint4v f; \
        f.x = __builtin_amdgcn_alignbit(d1, d0, sh); \
        f.y = __builtin_amdgcn_alignbit(d2, d1, sh); \
        f.z = __builtin_amdgcn_alignbit(d3, d2, sh); \
        f.w = __builtin_amdgcn_alignbit(d4, d3, sh); \
        if (w == 0) { f.x &= amask.x; f.y &= amask.y; f.z &= amask.z; f.w &= amask.w; } \
        av[w] = __builtin_bit_cast(short8, f); \
      } }

#define MFMA_NT(NT, bv0, bv1) \
    acc[0][NT] = __builtin_amdgcn_mfma_f32_16x16x32_bf16(av[0], bv0, acc[0][NT], 0,0,0); \
    acc[1][NT] = __builtin_amdgcn_mfma_f32_16x16x32_bf16(av[1], bv0, acc[1][NT], 0,0,0); \
    acc[2][NT] = __builtin_amdgcn_mfma_f32_16x16x32_bf16(av[2], bv0, acc[2][NT], 0,0,0); \
    acc[3][NT] = __builtin_amdgcn_mfma_f32_16x16x32_bf16(av[3], bv0, acc[3][NT], 0,0,0); \
    acc[1][NT] = __builtin_amdgcn_mfma_f32_16x16x32_bf16(av[0], bv1, acc[1][NT], 0,0,0); \
    acc[2][NT] = __builtin_amdgcn_mfma_f32_16x16x32_bf16(av[1], bv1, acc[2][NT], 0,0,0); \
    acc[3][NT] = __builtin_amdgcn_mfma_f32_16x16x32_bf16(av[2], bv1, acc[3][NT], 0,0,0);

    // FULL: p = i16+m-r+32nt guaranteed in [0,63] for all lanes.
#define NT_FULL(NT) { \
    const int p  = pmr + 32*(NT); \
    const int ba = (p << 7) + ((quad ^ (p & 7)) << 4); \
    const short8 bv0 = *(const short8*)(kpadB + ba); \
    const short8 bv1 = *(const short8*)(kpadB + (ba ^ 64)); \
    MFMA_NT(NT, bv0, bv1) }

    // PARTIAL: p may be outside [0,64): wrap address, zero the frag per-lane.
#define NT_PART(NT) { \
    const int pw = pmr + 32*(NT); \
    const int p  = pw & 63; \
    const int ba = (p << 7) + ((quad ^ (p & 7)) << 4); \
    short8 bv0 = *(const short8*)(kpadB + ba); \
    short8 bv1 = *(const short8*)(kpadB + (ba ^ 64)); \
    const bool keep = ((uint32)pw < 64u); \
    bv0 = keep ? bv0 : kzero; \
    bv1 = keep ? bv1 : kzero; \
    MFMA_NT(NT, bv0, bv1) }

#define SEG_BODY(...) { A_PHASE(r); const int pmr = i16 + m - r; __VA_ARGS__ }

    int r = 0;
    // S0 [0, i16]:        nt0 F, nt1 F     (trip 1 or 17)
#pragma unroll 2
    for (; r <= i16;       ++r) SEG_BODY(NT_FULL(0) NT_FULL(1))
    // S1 [i16+1, i16+15]: nt0 P, nt1 F, nt2 P
#pragma unroll 2
    for (; r <= i16 + 15;  ++r) SEG_BODY(NT_PART(0) NT_FULL(1) NT_PART(2))
    // S2 [i16+16, i16+32]: nt1 F, nt2 F
#pragma unroll 2
    for (; r <= i16 + 32;  ++r) SEG_BODY(NT_FULL(1) NT_FULL(2))
    // S3 [i16+33, i16+47]: nt1 P, nt2 F, nt3 P
#pragma unroll 2
    for (; r <= i16 + 47;  ++r) SEG_BODY(NT_PART(1) NT_FULL(2) NT_PART(3))
    // S4 [i16+48, i16+64]: nt2 F, nt3 F
#pragma unroll 2
    for (; r <= i16 + 64;  ++r) SEG_BODY(NT_FULL(2) NT_FULL(3))
    // S5 [i16+65, i16+79]: nt2 P, nt3 F
#pragma unroll 2
    for (; r <= i16 + 79;  ++r) SEG_BODY(NT_PART(2) NT_FULL(3))
    // S6 [i16+80, i16+96]: nt3 F
#pragma unroll 2
    for (; r <= i16 + 96;  ++r) SEG_BODY(NT_FULL(3))
    // S7 [i16+97, i16+111]: nt3 P
#pragma unroll 2
    for (; r <= i16 + 111; ++r) SEG_BODY(NT_PART(3))

#undef SEG_BODY
#undef NT_PART
#undef NT_FULL
#undef MFMA_NT
#undef A_PHASE

    // ---- epilogue: acc -> LDS transpose -> postgate * store ----
    // i = 32nt + 16iw + m ; j = 32mt + 16jw + 4quad + rg.
    __syncthreads();
    float (*bufE)[132] = (float(*)[132])smem;   // 64x132 fp32 = 33792 B
#pragma unroll
    for (int h = 0; h < 2; ++h) {               // i halves [0,64), [64,128)
#pragma unroll
        for (int ntl = 0; ntl < 2; ++ntl) {
            const int iloc = (ntl << 5) + i16 + m;
#pragma unroll
            for (int mt = 0; mt < 4; ++mt)
#pragma unroll
                for (int rg = 0; rg < 4; ++rg)
                    bufE[iloc][(mt << 5) + (jw << 4) + (quad << 2) + rg] =
                        acc[mt][(h << 1) + ntl][rg];
        }
        __syncthreads();
#pragma unroll 1
        for (int s = 0; s < 8; ++s) {
            int chunk = (s << 8) + tid;
            int row = chunk >> 5, c4 = (chunk & 31) << 2;
            float4 v = *(float4*)&bufE[row][c4];
            int gi = (h << 6) + row;
            const float4 g = *(const float4*)(gimg + gi*128 + c4);
            float4 o;
            o.x = v.x*g.x; o.y = v.y*g.y; o.z = v.z*g.z; o.w = v.w*g.w;
            *(float4*)(oimg + gi*128 + c4) = o;
        }
        __syncthreads();
    }
}

extern "C" void kernel_launch(void* const* d_in, const int* in_sizes, int n_in,
                              void* d_out, int out_size, void* d_ws, size_t ws_size,
                              hipStream_t stream) {
    const float* u    = (const float*)d_in[0];  // (4,256,128,128)
    const float* k    = (const float*)d_in[1];  // (256,64,64)
    const float* pre  = (const float*)d_in[2];  // (4,256,128,128)
    const float* post = (const float*)d_in[3];  // (4,256,128,128)
    float* out = (float*)d_out;                 // (4,256,128,128) fp32

    conv_mfma6<<<dim3(1024), dim3(256), SMEM_BYTES, stream>>>(u, k, pre, post, out);
}